// Round 1
// baseline (300.245 us; speedup 1.0000x reference)
//
#include <hip/hip_runtime.h>

#define N 2048
#define D 128
#define DK 64
#define DG 64
#define SD 8
#define TI 16
#define TJ 256

// ---------------- kernel 1: projections k = A@Wk+bk, q = A@Wq+bq, appear = A@Wv+bv
__global__ __launch_bounds__(128) void proj_kernel(
    const float* __restrict__ A,
    const float* __restrict__ Wv, const float* __restrict__ bv,
    const float* __restrict__ Wk, const float* __restrict__ bk,
    const float* __restrict__ Wq, const float* __restrict__ bq,
    float* __restrict__ kout, float* __restrict__ qout, float* __restrict__ vout)
{
    __shared__ float arow[D];
    const int i = blockIdx.x;
    const int t = threadIdx.x;
    arow[t] = A[(size_t)i * D + t];
    __syncthreads();
    for (int e = t; e < 2 * DK + SD; e += 128) {
        const float* W; const float* b; int od; int col;
        if (e < DK)            { W = Wk; b = bk; od = DK; col = e; }
        else if (e < 2 * DK)   { W = Wq; b = bq; od = DK; col = e - DK; }
        else                   { W = Wv; b = bv; od = SD; col = e - 2 * DK; }
        float acc = 0.f;
        #pragma unroll 8
        for (int c = 0; c < D; ++c) acc += arow[c] * W[c * od + col];
        acc += b[col];
        if (e < DK)          kout[(size_t)i * DK + col] = acc;
        else if (e < 2 * DK) qout[(size_t)i * DK + col] = acc;
        else                 vout[(size_t)i * SD + col] = acc;
    }
}

// ---------------- kernel 2: main gate kernel
// block tile: TI=16 rows x TJ=256 cols. 256 threads = 16 groups x 16 lanes.
// phase 1: wA[ii][jl] = exp((k_i . q_j)/8) into LDS
// phase 2: stream geometry, w_nom = relu(geom.Wg + bg)*wA, per-column partial sums.
__global__ __launch_bounds__(256) void gate_kernel(
    const float* __restrict__ geom,
    const float* __restrict__ Wg, const float* __restrict__ bg,
    const float* __restrict__ kin, const float* __restrict__ qin,
    float* __restrict__ w_nom, float* __restrict__ colpartial)
{
    __shared__ float wA[TI * TJ];      // 16 KB
    __shared__ float kt[TI * DK];      // 4 KB
    const int tid = threadIdx.x;
    const int j0 = blockIdx.x * TJ;
    const int i0 = blockIdx.y * TI;

    // stage k tile (rows i0..i0+15 are contiguous in k)
    for (int e = tid; e < TI * DK; e += 256) kt[e] = kin[(size_t)i0 * DK + e];
    __syncthreads();

    // phase 1: each thread owns column jl = tid
    {
        float acc[TI];
        #pragma unroll
        for (int r = 0; r < TI; ++r) acc[r] = 0.f;
        const float4* ktv = (const float4*)kt;
        const float4* qrow = (const float4*)(qin + (size_t)(j0 + tid) * DK);
        #pragma unroll
        for (int chunk = 0; chunk < 2; ++chunk) {
            float4 qv[8];
            #pragma unroll
            for (int m = 0; m < 8; ++m) qv[m] = qrow[chunk * 8 + m];
            #pragma unroll
            for (int r = 0; r < TI; ++r) {
                float p = 0.f;
                #pragma unroll
                for (int m = 0; m < 8; ++m) {
                    float4 kv = ktv[r * 16 + chunk * 8 + m];
                    p += kv.x * qv[m].x + kv.y * qv[m].y + kv.z * qv[m].z + kv.w * qv[m].w;
                }
                acc[r] += p;
            }
        }
        #pragma unroll
        for (int r = 0; r < TI; ++r) wA[r * TJ + tid] = expf(acc[r] * 0.125f);
    }
    __syncthreads();

    // phase 2
    const int group = tid >> 4;
    const int sub = tid & 15;
    const float4 wg4 = ((const float4*)Wg)[sub];
    const float bgv = bg[0];

    float colacc[16];
    #pragma unroll
    for (int cc = 0; cc < 16; ++cc) colacc[cc] = 0.f;

    for (int ii = 0; ii < TI; ++ii) {
        const int row = i0 + ii;
        const float4* grow = (const float4*)(geom + ((size_t)row * N + j0) * DG);
        #pragma unroll
        for (int cc = 0; cc < 16; ++cc) {
            const int jl = cc * 16 + group;
            float4 g4 = grow[(size_t)jl * 16 + sub];
            float s = g4.x * wg4.x + g4.y * wg4.y + g4.z * wg4.z + g4.w * wg4.w;
            // reduce across 16-lane group (groups are 16-lane aligned in the wave)
            s += __shfl_xor(s, 1);
            s += __shfl_xor(s, 2);
            s += __shfl_xor(s, 4);
            s += __shfl_xor(s, 8);
            s += bgv;
            s = s > 0.f ? s : 0.f;
            float val = s * wA[ii * TJ + jl];
            colacc[cc] += val;
            if (sub == 0) w_nom[(size_t)row * N + j0 + jl] = val;
        }
    }
    if (sub == 0) {
        #pragma unroll
        for (int cc = 0; cc < 16; ++cc)
            colpartial[(size_t)blockIdx.y * N + j0 + cc * 16 + group] = colacc[cc];
    }
}

// ---------------- kernel 3: reduce 128 column-partials -> colsum
__global__ __launch_bounds__(256) void colsum_kernel(
    const float* __restrict__ colpartial, float* __restrict__ colsum)
{
    const int j = blockIdx.x * 256 + threadIdx.x;
    float acc = 0.f;
    #pragma unroll 8
    for (int r = 0; r < 128; ++r) acc += colpartial[(size_t)r * N + j];
    colsum[j] = acc;
}

// ---------------- kernel 4: out[i,s] = sum_j w_nom[i,j]/colsum[j] * appear[j,s]
__global__ __launch_bounds__(256) void out_kernel(
    const float* __restrict__ w_nom, const float* __restrict__ colsum,
    const float* __restrict__ appear, float* __restrict__ out)
{
    const int i = blockIdx.x;
    const int t = threadIdx.x;
    float acc[SD];
    #pragma unroll
    for (int s = 0; s < SD; ++s) acc[s] = 0.f;

    for (int j = t; j < N; j += 256) {
        float wn = w_nom[(size_t)i * N + j];
        float inv = wn / colsum[j];
        const float4* ap = (const float4*)(appear + (size_t)j * SD);
        float4 a0 = ap[0], a1 = ap[1];
        acc[0] += inv * a0.x; acc[1] += inv * a0.y;
        acc[2] += inv * a0.z; acc[3] += inv * a0.w;
        acc[4] += inv * a1.x; acc[5] += inv * a1.y;
        acc[6] += inv * a1.z; acc[7] += inv * a1.w;
    }
    // wave reduce (64-wide)
    #pragma unroll
    for (int s = 0; s < SD; ++s) {
        #pragma unroll
        for (int off = 32; off >= 1; off >>= 1)
            acc[s] += __shfl_down(acc[s], off);
    }
    __shared__ float red[4][SD];
    const int wave = t >> 6;
    const int lane = t & 63;
    if (lane == 0) {
        #pragma unroll
        for (int s = 0; s < SD; ++s) red[wave][s] = acc[s];
    }
    __syncthreads();
    if (t < SD) out[(size_t)i * SD + t] = red[0][t] + red[1][t] + red[2][t] + red[3][t];
}

extern "C" void kernel_launch(void* const* d_in, const int* in_sizes, int n_in,
                              void* d_out, int out_size, void* d_ws, size_t ws_size,
                              hipStream_t stream) {
    const float* A    = (const float*)d_in[0];
    const float* geom = (const float*)d_in[1];
    const float* Wv   = (const float*)d_in[2];
    const float* bv   = (const float*)d_in[3];
    const float* Wk   = (const float*)d_in[4];
    const float* bk   = (const float*)d_in[5];
    const float* Wq   = (const float*)d_in[6];
    const float* bq   = (const float*)d_in[7];
    const float* Wg   = (const float*)d_in[8];
    const float* bg   = (const float*)d_in[9];
    float* out = (float*)d_out;

    float* ws = (float*)d_ws;
    float* kbuf       = ws;                               // N*DK
    float* qbuf       = kbuf + (size_t)N * DK;            // N*DK
    float* appear     = qbuf + (size_t)N * DK;            // N*SD
    float* w_nom      = appear + (size_t)N * SD;          // N*N
    float* colpartial = w_nom + (size_t)N * N;            // (N/TI)*N = 128*N
    float* colsum     = colpartial + (size_t)(N / TI) * N; // N

    proj_kernel<<<N, 128, 0, stream>>>(A, Wv, bv, Wk, bk, Wq, bq, kbuf, qbuf, appear);
    gate_kernel<<<dim3(N / TJ, N / TI), 256, 0, stream>>>(geom, Wg, bg, kbuf, qbuf,
                                                          w_nom, colpartial);
    colsum_kernel<<<N / 256, 256, 0, stream>>>(colpartial, colsum);
    out_kernel<<<N, 256, 0, stream>>>(w_nom, colsum, appear, out);
}

// Round 2
// 243.726 us; speedup vs baseline: 1.2319x; 1.2319x over previous
//
#include <hip/hip_runtime.h>

#define N 2048
#define D 128
#define DK 64
#define DG 64
#define SD 8
#define TI 8
#define TJ 256

typedef float f4v __attribute__((ext_vector_type(4)));

// ---------------- kernel 1: projections k = A@Wk+bk, q = A@Wq+bq, appear = A@Wv+bv
__global__ __launch_bounds__(128) void proj_kernel(
    const float* __restrict__ A,
    const float* __restrict__ Wv, const float* __restrict__ bv,
    const float* __restrict__ Wk, const float* __restrict__ bk,
    const float* __restrict__ Wq, const float* __restrict__ bq,
    float* __restrict__ kout, float* __restrict__ qout, float* __restrict__ vout)
{
    __shared__ float arow[D];
    const int i = blockIdx.x;
    const int t = threadIdx.x;
    arow[t] = A[(size_t)i * D + t];
    __syncthreads();
    for (int e = t; e < 2 * DK + SD; e += 128) {
        const float* W; const float* b; int od; int col;
        if (e < DK)            { W = Wk; b = bk; od = DK; col = e; }
        else if (e < 2 * DK)   { W = Wq; b = bq; od = DK; col = e - DK; }
        else                   { W = Wv; b = bv; od = SD; col = e - 2 * DK; }
        float acc = 0.f;
        #pragma unroll 8
        for (int c = 0; c < D; ++c) acc += arow[c] * W[c * od + col];
        acc += b[col];
        if (e < DK)          kout[(size_t)i * DK + col] = acc;
        else if (e < 2 * DK) qout[(size_t)i * DK + col] = acc;
        else                 vout[(size_t)i * SD + col] = acc;
    }
}

// ---------------- kernel 2: main gate kernel
// block tile: TI=8 rows x TJ=256 cols, 256 threads = 16 groups x 16 lanes.
// phase 1: wA[ii][jl] = exp((k_i . q_j)/8) into LDS
// phase 2: stream geometry (batched nt loads), w_nom = relu(geom.Wg+bg)*wA,
//          overwrite wA slot in place with w_nom value, per-column partials in regs.
// phase 3: coalesced flush of the 8KB tile to w_nom.
__global__ __launch_bounds__(256) void gate_kernel(
    const float* __restrict__ geom,
    const float* __restrict__ Wg, const float* __restrict__ bg,
    const float* __restrict__ kin, const float* __restrict__ qin,
    float* __restrict__ w_nom, float* __restrict__ colpartial)
{
    __shared__ float wA[TI * TJ];      // 8 KB: exp(wA) then w_nom values
    __shared__ float kt[TI * DK];      // 2 KB
    const int tid = threadIdx.x;
    const int j0 = blockIdx.x * TJ;
    const int i0 = blockIdx.y * TI;

    for (int e = tid; e < TI * DK; e += 256) kt[e] = kin[(size_t)i0 * DK + e];
    __syncthreads();

    // phase 1: each thread owns column jl = tid
    {
        float acc[TI];
        #pragma unroll
        for (int r = 0; r < TI; ++r) acc[r] = 0.f;
        const f4v* ktv = (const f4v*)kt;
        const f4v* qrow = (const f4v*)(qin + (size_t)(j0 + tid) * DK);
        f4v qv[16];
        #pragma unroll
        for (int m = 0; m < 16; ++m) qv[m] = qrow[m];
        #pragma unroll
        for (int r = 0; r < TI; ++r) {
            float p = 0.f;
            #pragma unroll
            for (int m = 0; m < 16; ++m) {
                f4v kv = ktv[r * 16 + m];
                p += kv.x * qv[m].x + kv.y * qv[m].y + kv.z * qv[m].z + kv.w * qv[m].w;
            }
            acc[r] = p;
        }
        #pragma unroll
        for (int r = 0; r < TI; ++r) wA[r * TJ + tid] = expf(acc[r] * 0.125f);
    }
    __syncthreads();

    // phase 2
    const int group = tid >> 4;
    const int sub = tid & 15;
    const f4v wg4 = ((const f4v*)Wg)[sub];
    const float bgv = bg[0];

    float colacc[16];
    #pragma unroll
    for (int cc = 0; cc < 16; ++cc) colacc[cc] = 0.f;

    for (int ii = 0; ii < TI; ++ii) {
        const f4v* grow = (const f4v*)(geom + ((size_t)(i0 + ii) * N + j0) * DG);
        f4v g[16];
        #pragma unroll
        for (int cc = 0; cc < 16; ++cc)
            g[cc] = __builtin_nontemporal_load(grow + (size_t)(cc * 16 + group) * 16 + sub);
        #pragma unroll
        for (int cc = 0; cc < 16; ++cc) {
            float s = g[cc].x * wg4.x + g[cc].y * wg4.y + g[cc].z * wg4.z + g[cc].w * wg4.w;
            s += __shfl_xor(s, 1);
            s += __shfl_xor(s, 2);
            s += __shfl_xor(s, 4);
            s += __shfl_xor(s, 8);
            s += bgv;
            s = fmaxf(s, 0.f);
            const int jl = cc * 16 + group;
            const float val = s * wA[ii * TJ + jl];   // all 16 lanes read (broadcast)
            colacc[cc] += val;
            if (sub == 0) wA[ii * TJ + jl] = val;     // in-place overwrite, same wave
        }
    }
    // column partials (all lanes of a group hold identical colacc after butterfly)
    if (sub == 0) {
        #pragma unroll
        for (int cc = 0; cc < 16; ++cc)
            colpartial[(size_t)blockIdx.y * N + j0 + cc * 16 + group] = colacc[cc];
    }
    __syncthreads();
    // phase 3: coalesced flush of w_nom tile (TI*TJ floats = 512 float4)
    {
        const f4v* src = (const f4v*)wA;
        #pragma unroll
        for (int r = 0; r < TI * TJ / 4; r += 256) {
            const int idx = r + tid;            // [0, 512)
            const int row = idx >> 6;           // TJ/4 = 64 float4 per row
            const int col = idx & 63;
            ((f4v*)(w_nom + (size_t)(i0 + row) * N + j0))[col] = src[idx];
        }
    }
}

// ---------------- kernel 3: reduce column-partials -> reciprocal of colsum
__global__ __launch_bounds__(256) void colsum_kernel(
    const float* __restrict__ colpartial, float* __restrict__ colrcp)
{
    const int j = blockIdx.x * 256 + threadIdx.x;
    float acc = 0.f;
    #pragma unroll 8
    for (int r = 0; r < N / TI; ++r) acc += colpartial[(size_t)r * N + j];
    colrcp[j] = 1.0f / acc;
}

// ---------------- kernel 4: out[i,s] = sum_j w_nom[i,j]*colrcp[j] * appear[j,s]
__global__ __launch_bounds__(256) void out_kernel(
    const float* __restrict__ w_nom, const float* __restrict__ colrcp,
    const float* __restrict__ appear, float* __restrict__ out)
{
    const int i = blockIdx.x;
    const int t = threadIdx.x;
    float acc[SD];
    #pragma unroll
    for (int s = 0; s < SD; ++s) acc[s] = 0.f;

    #pragma unroll
    for (int jj = 0; jj < N / (256 * 4); ++jj) {
        const int j4 = jj * 256 + t;                 // float4 index
        const f4v wn = ((const f4v*)(w_nom + (size_t)i * N))[j4];
        const f4v rc = ((const f4v*)colrcp)[j4];
        const float w0 = wn.x * rc.x, w1 = wn.y * rc.y, w2 = wn.z * rc.z, w3 = wn.w * rc.w;
        const int j = j4 * 4;
        const f4v* a0 = (const f4v*)(appear + (size_t)j * SD);
        f4v r0 = a0[0], r1 = a0[1];   // row j
        f4v r2 = a0[2], r3 = a0[3];   // row j+1
        f4v r4 = a0[4], r5 = a0[5];   // row j+2
        f4v r6 = a0[6], r7 = a0[7];   // row j+3
        acc[0] += w0 * r0.x + w1 * r2.x + w2 * r4.x + w3 * r6.x;
        acc[1] += w0 * r0.y + w1 * r2.y + w2 * r4.y + w3 * r6.y;
        acc[2] += w0 * r0.z + w1 * r2.z + w2 * r4.z + w3 * r6.z;
        acc[3] += w0 * r0.w + w1 * r2.w + w2 * r4.w + w3 * r6.w;
        acc[4] += w0 * r1.x + w1 * r3.x + w2 * r5.x + w3 * r7.x;
        acc[5] += w0 * r1.y + w1 * r3.y + w2 * r5.y + w3 * r7.y;
        acc[6] += w0 * r1.z + w1 * r3.z + w2 * r5.z + w3 * r7.z;
        acc[7] += w0 * r1.w + w1 * r3.w + w2 * r5.w + w3 * r7.w;
    }
    #pragma unroll
    for (int s = 0; s < SD; ++s) {
        #pragma unroll
        for (int off = 32; off >= 1; off >>= 1)
            acc[s] += __shfl_down(acc[s], off);
    }
    __shared__ float red[4][SD];
    const int wave = t >> 6;
    const int lane = t & 63;
    if (lane == 0) {
        #pragma unroll
        for (int s = 0; s < SD; ++s) red[wave][s] = acc[s];
    }
    __syncthreads();
    if (t < SD) out[(size_t)i * SD + t] = red[0][t] + red[1][t] + red[2][t] + red[3][t];
}

extern "C" void kernel_launch(void* const* d_in, const int* in_sizes, int n_in,
                              void* d_out, int out_size, void* d_ws, size_t ws_size,
                              hipStream_t stream) {
    const float* A    = (const float*)d_in[0];
    const float* geom = (const float*)d_in[1];
    const float* Wv   = (const float*)d_in[2];
    const float* bv   = (const float*)d_in[3];
    const float* Wk   = (const float*)d_in[4];
    const float* bk   = (const float*)d_in[5];
    const float* Wq   = (const float*)d_in[6];
    const float* bq   = (const float*)d_in[7];
    const float* Wg   = (const float*)d_in[8];
    const float* bg   = (const float*)d_in[9];
    float* out = (float*)d_out;

    float* ws = (float*)d_ws;
    float* kbuf       = ws;                                 // N*DK
    float* qbuf       = kbuf + (size_t)N * DK;              // N*DK
    float* appear     = qbuf + (size_t)N * DK;              // N*SD
    float* w_nom      = appear + (size_t)N * SD;            // N*N
    float* colpartial = w_nom + (size_t)N * N;              // (N/TI)*N
    float* colrcp     = colpartial + (size_t)(N / TI) * N;  // N

    proj_kernel<<<N, 128, 0, stream>>>(A, Wv, bv, Wk, bk, Wq, bq, kbuf, qbuf, appear);
    gate_kernel<<<dim3(N / TJ, N / TI), 256, 0, stream>>>(geom, Wg, bg, kbuf, qbuf,
                                                          w_nom, colpartial);
    colsum_kernel<<<N / 256, 256, 0, stream>>>(colpartial, colrcp);
    out_kernel<<<N, 256, 0, stream>>>(w_nom, colrcp, appear, out);
}